// Round 1
// baseline (155.403 us; speedup 1.0000x reference)
//
#include <hip/hip_runtime.h>

// DCT2D: out[b,c,u,v] = scale[u,v] * sum_{x,y} (in[b,c,x,y]-128) * c[x,u]*c[y,v]
// Separable with folded scale: cs[x][u] = c[x][u]*alpha[u]*0.5
//   t[u][y]  = sum_x (in[x][y]-128) * cs[x][u]
//   out[u][v]= sum_y t[u][y] * cs[y][v]
// Constants recovered exactly from inputs:
//   c[x][u]      = dct_tensor[x,0,u,0]          (c[0][0] == 1)
//   alpha[u]*0.5 = scale[u,0] * 2*sqrt(2)

__global__ __launch_bounds__(256) void dct2d_kernel(
    const float* __restrict__ x,
    const float* __restrict__ dct,     // [8,8,8,8] = c[x,u]*c[y,v]
    const float* __restrict__ scale,   // [8,8]
    float* __restrict__ out,
    int nblocks)
{
    int t = blockIdx.x * blockDim.x + threadIdx.x;
    if (t >= nblocks) return;

    // Build folded constant matrix cs[x][u] (wave-uniform -> scalar loads)
    float cs[8][8];
#pragma unroll
    for (int u = 0; u < 8; ++u) {
        float a = scale[u * 8] * 2.8284271247461903f;  // alpha[u]*0.5
#pragma unroll
        for (int xx = 0; xx < 8; ++xx) {
            cs[xx][u] = dct[xx * 512 + u * 8] * a;     // dct[x,0,u,0]*a
        }
    }

    const float* bp = x + (size_t)t * 64;

    float acc[8][8];  // acc[u][y]
#pragma unroll
    for (int u = 0; u < 8; ++u)
#pragma unroll
        for (int y = 0; y < 8; ++y) acc[u][y] = 0.0f;

    // Pass 1: over input rows xx, accumulate t[u][y] += cs[xx][u]*(o[xx][y]-128)
#pragma unroll
    for (int xx = 0; xx < 8; ++xx) {
        float4 r0 = *reinterpret_cast<const float4*>(bp + xx * 8);
        float4 r1 = *reinterpret_cast<const float4*>(bp + xx * 8 + 4);
        float o[8] = {r0.x - 128.0f, r0.y - 128.0f, r0.z - 128.0f, r0.w - 128.0f,
                      r1.x - 128.0f, r1.y - 128.0f, r1.z - 128.0f, r1.w - 128.0f};
#pragma unroll
        for (int u = 0; u < 8; ++u) {
            float c = cs[xx][u];
#pragma unroll
            for (int y = 0; y < 8; ++y) acc[u][y] = fmaf(c, o[y], acc[u][y]);
        }
    }

    // Pass 2: out[u][v] = sum_y acc[u][y]*cs[y][v]; store row-by-row
    float* op = out + (size_t)t * 64;
#pragma unroll
    for (int u = 0; u < 8; ++u) {
        float r[8];
#pragma unroll
        for (int v = 0; v < 8; ++v) {
            float s = 0.0f;
#pragma unroll
            for (int y = 0; y < 8; ++y) s = fmaf(acc[u][y], cs[y][v], s);
            r[v] = s;
        }
        *reinterpret_cast<float4*>(op + u * 8)     = make_float4(r[0], r[1], r[2], r[3]);
        *reinterpret_cast<float4*>(op + u * 8 + 4) = make_float4(r[4], r[5], r[6], r[7]);
    }
}

extern "C" void kernel_launch(void* const* d_in, const int* in_sizes, int n_in,
                              void* d_out, int out_size, void* d_ws, size_t ws_size,
                              hipStream_t stream)
{
    const float* x     = (const float*)d_in[0];
    const float* dct   = (const float*)d_in[1];
    const float* scale = (const float*)d_in[2];
    float* out = (float*)d_out;

    int nblocks = in_sizes[0] / 64;           // number of 8x8 tiles
    int nthreads = nblocks;
    int block = 256;
    int grid = (nthreads + block - 1) / block;

    dct2d_kernel<<<grid, block, 0, stream>>>(x, dct, scale, out, nblocks);
}

// Round 2
// 90.588 us; speedup vs baseline: 1.7155x; 1.7155x over previous
//
#include <hip/hip_runtime.h>

// DCT2D, 8 threads per 8x8 block (one image row each).
//   t[v]    = sum_y (o[row][y]-128) * cs[y][v]          (local, row-major load)
//   -- lane transpose --  lane r now holds t[x][v=r], x=0..7
//   res[u]  = sum_x t[x] * cs[x][u]                      (local)
//   -- lane transpose --  lane r now holds out[r][v], v=0..7
//   coalesced 32B store per lane.
// cs[a][b] = c[a][b]*alpha[b]*0.5, recovered exactly from inputs:
//   c[a][b]        = dct_tensor[a,0,b,0]   (c[0][0]==1)
//   alpha[b]*0.5   = scale[b,0] * 2*sqrt(2)

__device__ __forceinline__ void xpose8(float a[8], bool h1, bool h2, bool h4)
{
    // stage s=1
#pragma unroll
    for (int j = 0; j < 8; j += 2) {
        const int k = j + 1;
        float fj = __shfl_xor(a[k], 1);
        float fk = __shfl_xor(a[j], 1);
        float nj = h1 ? fj : a[j];
        float nk = h1 ? a[k] : fk;
        a[j] = nj; a[k] = nk;
    }
    // stage s=2
#pragma unroll
    for (int jj = 0; jj < 8; jj += 4) {
#pragma unroll
        for (int j0 = 0; j0 < 2; ++j0) {
            const int j = jj + j0, k = j + 2;
            float fj = __shfl_xor(a[k], 2);
            float fk = __shfl_xor(a[j], 2);
            float nj = h2 ? fj : a[j];
            float nk = h2 ? a[k] : fk;
            a[j] = nj; a[k] = nk;
        }
    }
    // stage s=4
#pragma unroll
    for (int j = 0; j < 4; ++j) {
        const int k = j + 4;
        float fj = __shfl_xor(a[k], 4);
        float fk = __shfl_xor(a[j], 4);
        float nj = h4 ? fj : a[j];
        float nk = h4 ? a[k] : fk;
        a[j] = nj; a[k] = nk;
    }
}

__global__ __launch_bounds__(256) void dct2d_kernel(
    const float* __restrict__ x,
    const float* __restrict__ dct,     // [8,8,8,8] = c[x,u]*c[y,v]
    const float* __restrict__ scale,   // [8,8]
    float* __restrict__ out,
    int nblocks)
{
    const int tid  = blockIdx.x * blockDim.x + threadIdx.x;
    const int lane = tid & 7;                    // which row of the 8x8 block
    const int nthreads = gridDim.x * blockDim.x;
    const int bstride  = nthreads >> 3;

    // wave-uniform folded constant matrix (expect SGPR allocation)
    float cs[8][8];
#pragma unroll
    for (int b = 0; b < 8; ++b) {
        const float a05 = scale[b * 8] * 2.8284271247461903f;  // alpha[b]*0.5
#pragma unroll
        for (int a = 0; a < 8; ++a)
            cs[a][b] = dct[a * 512 + b * 8] * a05;             // c[a][b]*a05
    }

    const bool h1 = (lane & 1) != 0;
    const bool h2 = (lane & 2) != 0;
    const bool h4 = (lane & 4) != 0;

    for (int b = (tid >> 3); b < nblocks; b += bstride) {
        const float* rp = x + (size_t)b * 64 + lane * 8;
        float4 q0 = *reinterpret_cast<const float4*>(rp);
        float4 q1 = *reinterpret_cast<const float4*>(rp + 4);
        float o[8] = {q0.x - 128.0f, q0.y - 128.0f, q0.z - 128.0f, q0.w - 128.0f,
                      q1.x - 128.0f, q1.y - 128.0f, q1.z - 128.0f, q1.w - 128.0f};

        // 1-D DCT along y (thread-local): t[v] = sum_y o[y]*cs[y][v]
        float t[8];
#pragma unroll
        for (int v = 0; v < 8; ++v) {
            float s = 0.0f;
#pragma unroll
            for (int y = 0; y < 8; ++y) s = fmaf(o[y], cs[y][v], s);
            t[v] = s;
        }

        // transpose across the 8-lane group: lane r now holds t[x][v=r]
        xpose8(t, h1, h2, h4);

        // 1-D DCT along x (thread-local): res[u] = sum_x t[x]*cs[x][u]
        float res[8];
#pragma unroll
        for (int u = 0; u < 8; ++u) {
            float s = 0.0f;
#pragma unroll
            for (int xx = 0; xx < 8; ++xx) s = fmaf(t[xx], cs[xx][u], s);
            res[u] = s;
        }

        // transpose back: lane r holds out[row r][v], v=0..7
        xpose8(res, h1, h2, h4);

        float* op = out + (size_t)b * 64 + lane * 8;
        *reinterpret_cast<float4*>(op)     = make_float4(res[0], res[1], res[2], res[3]);
        *reinterpret_cast<float4*>(op + 4) = make_float4(res[4], res[5], res[6], res[7]);
    }
}

extern "C" void kernel_launch(void* const* d_in, const int* in_sizes, int n_in,
                              void* d_out, int out_size, void* d_ws, size_t ws_size,
                              hipStream_t stream)
{
    const float* x     = (const float*)d_in[0];
    const float* dct   = (const float*)d_in[1];
    const float* scale = (const float*)d_in[2];
    float* out = (float*)d_out;

    int nblocks = in_sizes[0] / 64;   // number of 8x8 tiles (262144*3)
    int block = 256;
    int grid  = 2048;                 // grid-stride; 2048*256/8 = 65536 blocks/sweep

    dct2d_kernel<<<grid, block, 0, stream>>>(x, dct, scale, out, nblocks);
}

// Round 4
// 79.516 us; speedup vs baseline: 1.9544x; 1.1392x over previous
//
#include <hip/hip_runtime.h>

// DCT2D, 8 threads per 8x8 block (one image row each).
//   t[v]    = sum_y (o[row][y]-128) * cs[y][v]          (local, row-major load)
//   -- lane transpose --  lane r now holds t[x][v=r], x=0..7
//   res[u]  = sum_x t[x] * cs[x][u]                      (local)
//   -- lane transpose --  lane r now holds out[r][v], v=0..7
//   coalesced 32B nontemporal store per lane (output never re-read; keep L3 for input).
// cs[a][b] = c[a][b]*alpha[b]*0.5, recovered exactly from inputs:
//   c[a][b]        = dct_tensor[a,0,b,0]   (c[0][0]==1)
//   alpha[b]*0.5   = scale[b,0] * 2*sqrt(2)
// cs is wave-uniform -> forced to SGPRs via readfirstlane (VGPR budget -> 8 waves/SIMD).

typedef float vfloat4 __attribute__((ext_vector_type(4)));  // native vector for nontemporal builtin

__device__ __forceinline__ float uniformf(float v)
{
    return __int_as_float(__builtin_amdgcn_readfirstlane(__float_as_int(v)));
}

__device__ __forceinline__ void xpose8(float a[8], bool h1, bool h2, bool h4)
{
    // stage s=1
#pragma unroll
    for (int j = 0; j < 8; j += 2) {
        const int k = j + 1;
        float fj = __shfl_xor(a[k], 1);
        float fk = __shfl_xor(a[j], 1);
        float nj = h1 ? fj : a[j];
        float nk = h1 ? a[k] : fk;
        a[j] = nj; a[k] = nk;
    }
    // stage s=2
#pragma unroll
    for (int jj = 0; jj < 8; jj += 4) {
#pragma unroll
        for (int j0 = 0; j0 < 2; ++j0) {
            const int j = jj + j0, k = j + 2;
            float fj = __shfl_xor(a[k], 2);
            float fk = __shfl_xor(a[j], 2);
            float nj = h2 ? fj : a[j];
            float nk = h2 ? a[k] : fk;
            a[j] = nj; a[k] = nk;
        }
    }
    // stage s=4
#pragma unroll
    for (int j = 0; j < 4; ++j) {
        const int k = j + 4;
        float fj = __shfl_xor(a[k], 4);
        float fk = __shfl_xor(a[j], 4);
        float nj = h4 ? fj : a[j];
        float nk = h4 ? a[k] : fk;
        a[j] = nj; a[k] = nk;
    }
}

__global__ __launch_bounds__(256) void dct2d_kernel(
    const float* __restrict__ x,
    const float* __restrict__ dct,     // [8,8,8,8] = c[x,u]*c[y,v]
    const float* __restrict__ scale,   // [8,8]
    float* __restrict__ out,
    int nblocks)
{
    const int tid  = blockIdx.x * blockDim.x + threadIdx.x;
    const int lane = tid & 7;                    // which row of the 8x8 block
    const int nthreads = gridDim.x * blockDim.x;
    const int bstride  = nthreads >> 3;

    // wave-uniform folded constant matrix, forced to SGPRs
    float cs[8][8];
#pragma unroll
    for (int b = 0; b < 8; ++b) {
        const float a05 = scale[b * 8] * 2.8284271247461903f;  // alpha[b]*0.5
#pragma unroll
        for (int a = 0; a < 8; ++a)
            cs[a][b] = uniformf(dct[a * 512 + b * 8] * a05);   // c[a][b]*a05
    }

    const bool h1 = (lane & 1) != 0;
    const bool h2 = (lane & 2) != 0;
    const bool h4 = (lane & 4) != 0;

    for (int b = (tid >> 3); b < nblocks; b += bstride) {
        const float* rp = x + (size_t)b * 64 + lane * 8;
        float4 q0 = *reinterpret_cast<const float4*>(rp);
        float4 q1 = *reinterpret_cast<const float4*>(rp + 4);
        float o[8] = {q0.x - 128.0f, q0.y - 128.0f, q0.z - 128.0f, q0.w - 128.0f,
                      q1.x - 128.0f, q1.y - 128.0f, q1.z - 128.0f, q1.w - 128.0f};

        // 1-D DCT along y (thread-local): t[v] = sum_y o[y]*cs[y][v]
        float t[8];
#pragma unroll
        for (int v = 0; v < 8; ++v) {
            float s = 0.0f;
#pragma unroll
            for (int y = 0; y < 8; ++y) s = fmaf(o[y], cs[y][v], s);
            t[v] = s;
        }

        // transpose across the 8-lane group: lane r now holds t[x][v=r]
        xpose8(t, h1, h2, h4);

        // 1-D DCT along x (thread-local): res[u] = sum_x t[x]*cs[x][u]
        float res[8];
#pragma unroll
        for (int u = 0; u < 8; ++u) {
            float s = 0.0f;
#pragma unroll
            for (int xx = 0; xx < 8; ++xx) s = fmaf(t[xx], cs[xx][u], s);
            res[u] = s;
        }

        // transpose back: lane r holds out[row r][v], v=0..7
        xpose8(res, h1, h2, h4);

        float* op = out + (size_t)b * 64 + lane * 8;
        vfloat4 s0 = { res[0], res[1], res[2], res[3] };
        vfloat4 s1 = { res[4], res[5], res[6], res[7] };
        __builtin_nontemporal_store(s0, reinterpret_cast<vfloat4*>(op));
        __builtin_nontemporal_store(s1, reinterpret_cast<vfloat4*>(op + 4));
    }
}

extern "C" void kernel_launch(void* const* d_in, const int* in_sizes, int n_in,
                              void* d_out, int out_size, void* d_ws, size_t ws_size,
                              hipStream_t stream)
{
    const float* x     = (const float*)d_in[0];
    const float* dct   = (const float*)d_in[1];
    const float* scale = (const float*)d_in[2];
    float* out = (float*)d_out;

    int nblocks = in_sizes[0] / 64;   // number of 8x8 tiles (262144*3)
    int block = 256;
    int grid  = 2048;                 // grid-stride; 2048*256/8 = 65536 blocks/sweep

    dct2d_kernel<<<grid, block, 0, stream>>>(x, dct, scale, out, nblocks);
}